// Round 18
// baseline (150.861 us; speedup 1.0000x reference)
//
#include <hip/hip_runtime.h>
#include <hip/hip_bf16.h>

#define BN 2048      // B*N
#define NSEQ 512
#define D 256
#define H 128
#define R 16
#define AC 5

// ---------------- Kernel 1: per-row atom head + pj projection (jax orientation, f32 out) ----------------
__global__ __launch_bounds__(256) void row_kernel(
    const float* __restrict__ trunk, const int* __restrict__ pad,
    const float* __restrict__ ln_g, const float* __restrict__ ln_b,
    const float* __restrict__ w_a1, const float* __restrict__ b_a1,
    const float* __restrict__ w_a2, const float* __restrict__ b_a2,
    const float* __restrict__ w_pj,
    float* __restrict__ out_atom, float* __restrict__ pj_o)
{
    const int row = blockIdx.x;   // b*NSEQ + i
    const int tid = threadIdx.x;
    __shared__ float x[D];
    __shared__ float xn[D];
    __shared__ float y[D];
    __shared__ float r1[256];
    __shared__ float r2[256];

    const float xv = trunk[(size_t)row * D + tid];
    x[tid] = xv;
    r1[tid] = xv;
    r2[tid] = xv * xv;
    __syncthreads();
    for (int s = 128; s > 0; s >>= 1) {
        if (tid < s) { r1[tid] += r1[tid + s]; r2[tid] += r2[tid + s]; }
        __syncthreads();
    }
    const float mu   = r1[0] * (1.0f / D);
    const float var  = r2[0] * (1.0f / D) - mu * mu;
    const float rstd = rsqrtf(var + 1e-5f);
    xn[tid] = (xv - mu) * rstd * ln_g[tid] + ln_b[tid];
    __syncthreads();

    // a1 (jax): out[t] = b_a1[t] + sum_d xn[d] * W1[d*D + t]
    float acc = b_a1[tid];
    #pragma unroll 4
    for (int d = 0; d < D; ++d) acc = fmaf(xn[d], w_a1[d * D + tid], acc);
    y[tid] = acc / (1.0f + expf(-acc));

    // pj (jax): p[h] = sum_d x[d] * Wpj[d*H + h]   (threads 128..255)
    float p = 0.0f;
    if (tid >= H) {
        const int h = tid - H;
        #pragma unroll 4
        for (int d = 0; d < D; ++d) p = fmaf(x[d], w_pj[d * H + h], p);
    }
    __syncthreads();  // y fully written
    if (tid >= H) pj_o[(size_t)row * H + (tid - H)] = p;

    if (tid < AC) {
        float a = b_a2[tid];
        #pragma unroll 4
        for (int d = 0; d < D; ++d) a = fmaf(y[d], w_a2[d * AC + tid], a);
        out_atom[row * AC + tid] = (pad[row] != 0) ? 0.0f : a;
    }
}

// ---------------- Kernel 2: pair head — SUM over VALID j != i (raw sums to ws) ----------------
__global__ __launch_bounds__(256) void pair_kernel(
    const float* __restrict__ trunk, const float* __restrict__ coords,
    const int* __restrict__ pad,
    const float* __restrict__ w_pi, const float* __restrict__ w_pr,
    const float* __restrict__ b_p1, const float* __restrict__ w_p2,
    const float* __restrict__ b_p2,
    const float* __restrict__ pj_i,
    float* __restrict__ cd_raw)
{
    const int row = blockIdx.x;
    const int b = row >> 9, i = row & (NSEQ - 1);
    const int tid = threadIdx.x;

    if (pad[row] != 0) {
        if (tid == 0) {
            cd_raw[row * 3 + 0] = 0.0f;
            cd_raw[row * 3 + 1] = 0.0f;
            cd_raw[row * 3 + 2] = 0.0f;
        }
        return;
    }

    __shared__ __align__(16) float s_wpr[R * H];
    __shared__ __align__(16) float s_pib[H];
    __shared__ __align__(16) float s_wp2[H];
    __shared__ float s_xi[D];
    __shared__ float s_cj[NSEQ * 3];
    __shared__ int   s_val[NSEQ];
    __shared__ float r1[256], r2[256], r3[256];

    for (int k = tid; k < R * H; k += 256) s_wpr[k] = w_pr[k];
    s_xi[tid] = trunk[(size_t)row * D + tid];
    if (tid < H) s_wp2[tid] = w_p2[tid];
    for (int k = tid; k < NSEQ; k += 256) {
        s_val[k] = (pad[b * NSEQ + k] == 0);
        s_cj[k * 3 + 0] = coords[(b * NSEQ + k) * 3 + 0];
        s_cj[k * 3 + 1] = coords[(b * NSEQ + k) * 3 + 1];
        s_cj[k * 3 + 2] = coords[(b * NSEQ + k) * 3 + 2];
    }
    __syncthreads();

    if (tid < H) {
        float p = b_p1[tid];
        #pragma unroll 4
        for (int d = 0; d < D; ++d) p = fmaf(s_xi[d], w_pi[d * H + tid], p);
        s_pib[tid] = p;
    }
    __syncthreads();

    float cdx = 0.0f, cdy = 0.0f, cdz = 0.0f;
    {
        const float cix = s_cj[i * 3], ciy = s_cj[i * 3 + 1], ciz = s_cj[i * 3 + 2];
        const float bp2 = b_p2[0];
        const float gamma = 14.0625f;  // (15/4)^2
        for (int jj = 0; jj < 2; ++jj) {
            const int j = tid + jj * 256;
            if (j == i || !s_val[j]) continue;   // VALID j only
            const float dx = cix - s_cj[j * 3];
            const float dy = ciy - s_cj[j * 3 + 1];
            const float dz = ciz - s_cj[j * 3 + 2];
            const float sq = dx * dx + dy * dy + dz * dz;
            const float dist = sqrtf(fmaxf(sq, 1e-12f));
            float rbf[R];
            #pragma unroll
            for (int r = 0; r < R; ++r) {
                const float t = dist - (float)(4.0 * r / 15.0);
                rbf[r] = expf(-gamma * t * t);
            }
            const float* pjrow = pj_i + (size_t)(b * NSEQ + j) * H;
            float ssum = 0.0f;
            for (int h = 0; h < H; h += 8) {
                const float4 p0 = *(const float4*)(pjrow + h);
                const float4 p1 = *(const float4*)(pjrow + h + 4);
                const float4 a0 = *(const float4*)(s_pib + h);
                const float4 a1 = *(const float4*)(s_pib + h + 4);
                float t0 = a0.x + p0.x, t1 = a0.y + p0.y;
                float t2 = a0.z + p0.z, t3 = a0.w + p0.w;
                float t4 = a1.x + p1.x, t5 = a1.y + p1.y;
                float t6 = a1.z + p1.z, t7 = a1.w + p1.w;
                #pragma unroll
                for (int r = 0; r < R; ++r) {
                    const float rv = rbf[r];
                    const float4 w0 = *(const float4*)(s_wpr + r * H + h);
                    const float4 w1 = *(const float4*)(s_wpr + r * H + h + 4);
                    t0 = fmaf(rv, w0.x, t0);
                    t1 = fmaf(rv, w0.y, t1);
                    t2 = fmaf(rv, w0.z, t2);
                    t3 = fmaf(rv, w0.w, t3);
                    t4 = fmaf(rv, w1.x, t4);
                    t5 = fmaf(rv, w1.y, t5);
                    t6 = fmaf(rv, w1.z, t6);
                    t7 = fmaf(rv, w1.w, t7);
                }
                const float4 w20 = *(const float4*)(s_wp2 + h);
                const float4 w21 = *(const float4*)(s_wp2 + h + 4);
                t0 = t0 / (1.0f + expf(-t0));
                t1 = t1 / (1.0f + expf(-t1));
                t2 = t2 / (1.0f + expf(-t2));
                t3 = t3 / (1.0f + expf(-t3));
                t4 = t4 / (1.0f + expf(-t4));
                t5 = t5 / (1.0f + expf(-t5));
                t6 = t6 / (1.0f + expf(-t6));
                t7 = t7 / (1.0f + expf(-t7));
                ssum += t0 * w20.x + t1 * w20.y + t2 * w20.z + t3 * w20.w
                      + t4 * w21.x + t5 * w21.y + t6 * w21.z + t7 * w21.w;
            }
            const float pw = ssum + bp2;
            cdx = fmaf(pw, dx, cdx);
            cdy = fmaf(pw, dy, cdy);
            cdz = fmaf(pw, dz, cdz);
        }
    }
    r1[tid] = cdx; r2[tid] = cdy; r3[tid] = cdz;
    __syncthreads();
    for (int s = 128; s > 0; s >>= 1) {
        if (tid < s) { r1[tid] += r1[tid + s]; r2[tid] += r2[tid + s]; r3[tid] += r3[tid + s]; }
        __syncthreads();
    }
    if (tid == 0) {
        cd_raw[row * 3 + 0] = r1[0];
        cd_raw[row * 3 + 1] = r2[0];
        cd_raw[row * 3 + 2] = r3[0];
    }
}

// ---------------- Kernel 3: PROPER jax finalize ----------------
// cd2 = cd_raw / denom  (denom = max(count_valid,1));
// mean = sum_valid(cd2) / denom;  out = valid ? cd2 - mean : 0.
__global__ __launch_bounds__(256) void finalize_kernel(
    const float* __restrict__ cd_raw, const int* __restrict__ pad,
    float* __restrict__ out_coord)
{
    const int b = blockIdx.x;
    const int tid = threadIdx.x;
    __shared__ float r1[256], r2[256], r3[256], r4[256];
    float sx = 0.0f, sy = 0.0f, sz = 0.0f, cnt = 0.0f;
    for (int ii = tid; ii < NSEQ; ii += 256) {
        if (pad[b * NSEQ + ii] == 0) {
            sx += cd_raw[(b * NSEQ + ii) * 3 + 0];
            sy += cd_raw[(b * NSEQ + ii) * 3 + 1];
            sz += cd_raw[(b * NSEQ + ii) * 3 + 2];
            cnt += 1.0f;
        }
    }
    r1[tid] = sx; r2[tid] = sy; r3[tid] = sz; r4[tid] = cnt;
    __syncthreads();
    for (int s = 128; s > 0; s >>= 1) {
        if (tid < s) {
            r1[tid] += r1[tid + s]; r2[tid] += r2[tid + s];
            r3[tid] += r3[tid + s]; r4[tid] += r4[tid + s];
        }
        __syncthreads();
    }
    const float denom = fmaxf(r4[0], 1.0f);
    const float inv_d = 1.0f / denom;
    // mean = (sum_valid cd_raw / denom) / denom
    const float mx = r1[0] * inv_d * inv_d;
    const float my = r2[0] * inv_d * inv_d;
    const float mz = r3[0] * inv_d * inv_d;
    for (int ii = tid; ii < NSEQ; ii += 256) {
        const bool v = (pad[b * NSEQ + ii] == 0);
        out_coord[(b * NSEQ + ii) * 3 + 0] = v ? cd_raw[(b * NSEQ + ii) * 3 + 0] * inv_d - mx : 0.0f;
        out_coord[(b * NSEQ + ii) * 3 + 1] = v ? cd_raw[(b * NSEQ + ii) * 3 + 1] * inv_d - my : 0.0f;
        out_coord[(b * NSEQ + ii) * 3 + 2] = v ? cd_raw[(b * NSEQ + ii) * 3 + 2] * inv_d - mz : 0.0f;
    }
}

extern "C" void kernel_launch(void* const* d_in, const int* in_sizes, int n_in,
                              void* d_out, int out_size, void* d_ws, size_t ws_size,
                              hipStream_t stream) {
    const float* trunk  = (const float*)d_in[0];
    const float* coords = (const float*)d_in[1];
    const int*   pad    = (const int*)d_in[2];
    const float* ln_g   = (const float*)d_in[3];
    const float* ln_b   = (const float*)d_in[4];
    const float* w_a1   = (const float*)d_in[5];
    const float* b_a1   = (const float*)d_in[6];
    const float* w_a2   = (const float*)d_in[7];
    const float* b_a2   = (const float*)d_in[8];
    const float* w_pi   = (const float*)d_in[9];
    const float* w_pj   = (const float*)d_in[10];
    const float* w_pr   = (const float*)d_in[11];
    const float* b_p1   = (const float*)d_in[12];
    const float* w_p2   = (const float*)d_in[13];
    const float* b_p2   = (const float*)d_in[14];

    float* out_atom  = (float*)d_out;                 // f32 [0:10240]
    float* out_coord = out_atom + (size_t)BN * AC;    // f32 [10240:16384]

    float* cd_raw = (float*)d_ws;
    float* pj_buf = cd_raw + (size_t)BN * 3;

    row_kernel<<<BN, 256, 0, stream>>>(trunk, pad, ln_g, ln_b, w_a1, b_a1,
                                       w_a2, b_a2, w_pj, out_atom, pj_buf);
    pair_kernel<<<BN, 256, 0, stream>>>(trunk, coords, pad, w_pi, w_pr, b_p1,
                                        w_p2, b_p2, pj_buf, cd_raw);
    finalize_kernel<<<4, 256, 0, stream>>>(cd_raw, pad, out_coord);
}

// Round 19
// 121.963 us; speedup vs baseline: 1.2369x; 1.2369x over previous
//
#include <hip/hip_runtime.h>
#include <hip/hip_bf16.h>

#define BN 2048      // B*N
#define NSEQ 512
#define D 256
#define H 128
#define R 16
#define AC 5

// ---------------- Kernel 1: per-row atom head + pj projection (unchanged, passes) ----------------
__global__ __launch_bounds__(256) void row_kernel(
    const float* __restrict__ trunk, const int* __restrict__ pad,
    const float* __restrict__ ln_g, const float* __restrict__ ln_b,
    const float* __restrict__ w_a1, const float* __restrict__ b_a1,
    const float* __restrict__ w_a2, const float* __restrict__ b_a2,
    const float* __restrict__ w_pj,
    float* __restrict__ out_atom, float* __restrict__ pj_o)
{
    const int row = blockIdx.x;   // b*NSEQ + i
    const int tid = threadIdx.x;
    __shared__ float x[D];
    __shared__ float xn[D];
    __shared__ float y[D];
    __shared__ float r1[256];
    __shared__ float r2[256];

    const float xv = trunk[(size_t)row * D + tid];
    x[tid] = xv;
    r1[tid] = xv;
    r2[tid] = xv * xv;
    __syncthreads();
    for (int s = 128; s > 0; s >>= 1) {
        if (tid < s) { r1[tid] += r1[tid + s]; r2[tid] += r2[tid + s]; }
        __syncthreads();
    }
    const float mu   = r1[0] * (1.0f / D);
    const float var  = r2[0] * (1.0f / D) - mu * mu;
    const float rstd = rsqrtf(var + 1e-5f);
    xn[tid] = (xv - mu) * rstd * ln_g[tid] + ln_b[tid];
    __syncthreads();

    float acc = b_a1[tid];
    #pragma unroll 4
    for (int d = 0; d < D; ++d) acc = fmaf(xn[d], w_a1[d * D + tid], acc);
    y[tid] = acc / (1.0f + expf(-acc));

    float p = 0.0f;
    if (tid >= H) {
        const int h = tid - H;
        #pragma unroll 4
        for (int d = 0; d < D; ++d) p = fmaf(x[d], w_pj[d * H + h], p);
    }
    __syncthreads();
    if (tid >= H) pj_o[(size_t)row * H + (tid - H)] = p;

    if (tid < AC) {
        float a = b_a2[tid];
        #pragma unroll 4
        for (int d = 0; d < D; ++d) a = fmaf(y[d], w_a2[d * AC + tid], a);
        out_atom[row * AC + tid] = (pad[row] != 0) ? 0.0f : a;
    }
}

// ---------------- Kernel 2: pair head — compacted valid-j + __expf ----------------
__global__ __launch_bounds__(256) void pair_kernel(
    const float* __restrict__ trunk, const float* __restrict__ coords,
    const int* __restrict__ pad,
    const float* __restrict__ w_pi, const float* __restrict__ w_pr,
    const float* __restrict__ b_p1, const float* __restrict__ w_p2,
    const float* __restrict__ b_p2,
    const float* __restrict__ pj_i,
    float* __restrict__ cd_raw)
{
    const int row = blockIdx.x;
    const int b = row >> 9, i = row & (NSEQ - 1);
    const int tid = threadIdx.x;

    if (pad[row] != 0) {
        if (tid == 0) {
            cd_raw[row * 3 + 0] = 0.0f;
            cd_raw[row * 3 + 1] = 0.0f;
            cd_raw[row * 3 + 2] = 0.0f;
        }
        return;
    }

    __shared__ __align__(16) float s_wpr[R * H];
    __shared__ __align__(16) float s_pib[H];
    __shared__ __align__(16) float s_wp2[H];
    __shared__ float s_xi[D];
    __shared__ float s_cj[NSEQ * 3];
    __shared__ int   s_val[NSEQ];
    __shared__ int   s_jlist[NSEQ];
    __shared__ int   s_wcnt[8];
    __shared__ int   s_wbase[8];
    __shared__ int   s_M;
    __shared__ float r1[256], r2[256], r3[256];

    for (int k = tid; k < R * H; k += 256) s_wpr[k] = w_pr[k];
    s_xi[tid] = trunk[(size_t)row * D + tid];
    if (tid < H) s_wp2[tid] = w_p2[tid];
    for (int k = tid; k < NSEQ; k += 256) {
        s_val[k] = (pad[b * NSEQ + k] == 0);
        s_cj[k * 3 + 0] = coords[(b * NSEQ + k) * 3 + 0];
        s_cj[k * 3 + 1] = coords[(b * NSEQ + k) * 3 + 1];
        s_cj[k * 3 + 2] = coords[(b * NSEQ + k) * 3 + 2];
    }
    __syncthreads();

    // pi (jax): p[h] = b_p1[h] + sum_d xi[d] * Wpi[d*H + h]
    if (tid < H) {
        float p = b_p1[tid];
        #pragma unroll 4
        for (int d = 0; d < D; ++d) p = fmaf(s_xi[d], w_pi[d * H + tid], p);
        s_pib[tid] = p;
    }

    // ---- deterministic wave-ballot compaction of valid j (j != i) ----
    const int wv = tid >> 6, lane = tid & 63;
    unsigned long long bm[2];
    #pragma unroll
    for (int cc = 0; cc < 2; ++cc) {
        const int j = cc * 256 + tid;
        const int ok = (j != i) && s_val[j];
        bm[cc] = __ballot(ok);
        if (lane == 0) s_wcnt[cc * 4 + wv] = __popcll(bm[cc]);
    }
    __syncthreads();
    if (tid == 0) {
        int acc = 0;
        #pragma unroll
        for (int q = 0; q < 8; ++q) { s_wbase[q] = acc; acc += s_wcnt[q]; }
        s_M = acc;
    }
    __syncthreads();
    #pragma unroll
    for (int cc = 0; cc < 2; ++cc) {
        const int j = cc * 256 + tid;
        if ((j != i) && s_val[j]) {
            const int pos = s_wbase[cc * 4 + wv]
                          + __popcll(bm[cc] & ((1ull << lane) - 1ull));
            s_jlist[pos] = j;
        }
    }
    __syncthreads();
    const int M = s_M;

    float cdx = 0.0f, cdy = 0.0f, cdz = 0.0f;
    {
        const float cix = s_cj[i * 3], ciy = s_cj[i * 3 + 1], ciz = s_cj[i * 3 + 2];
        const float bp2 = b_p2[0];
        const float gamma = 14.0625f;  // (15/4)^2
        for (int k = tid; k < M; k += 256) {
            const int j = s_jlist[k];
            const float dx = cix - s_cj[j * 3];
            const float dy = ciy - s_cj[j * 3 + 1];
            const float dz = ciz - s_cj[j * 3 + 2];
            const float sq = dx * dx + dy * dy + dz * dz;
            const float dist = sqrtf(fmaxf(sq, 1e-12f));
            float rbf[R];
            #pragma unroll
            for (int r = 0; r < R; ++r) {
                const float t = dist - (float)(4.0 * r / 15.0);
                rbf[r] = __expf(-gamma * t * t);
            }
            const float* pjrow = pj_i + (size_t)(b * NSEQ + j) * H;
            float ssum = 0.0f;
            for (int h = 0; h < H; h += 8) {
                const float4 p0 = *(const float4*)(pjrow + h);
                const float4 p1 = *(const float4*)(pjrow + h + 4);
                const float4 a0 = *(const float4*)(s_pib + h);
                const float4 a1 = *(const float4*)(s_pib + h + 4);
                float t0 = a0.x + p0.x, t1 = a0.y + p0.y;
                float t2 = a0.z + p0.z, t3 = a0.w + p0.w;
                float t4 = a1.x + p1.x, t5 = a1.y + p1.y;
                float t6 = a1.z + p1.z, t7 = a1.w + p1.w;
                #pragma unroll
                for (int r = 0; r < R; ++r) {
                    const float rv = rbf[r];
                    const float4 w0 = *(const float4*)(s_wpr + r * H + h);
                    const float4 w1 = *(const float4*)(s_wpr + r * H + h + 4);
                    t0 = fmaf(rv, w0.x, t0);
                    t1 = fmaf(rv, w0.y, t1);
                    t2 = fmaf(rv, w0.z, t2);
                    t3 = fmaf(rv, w0.w, t3);
                    t4 = fmaf(rv, w1.x, t4);
                    t5 = fmaf(rv, w1.y, t5);
                    t6 = fmaf(rv, w1.z, t6);
                    t7 = fmaf(rv, w1.w, t7);
                }
                const float4 w20 = *(const float4*)(s_wp2 + h);
                const float4 w21 = *(const float4*)(s_wp2 + h + 4);
                t0 = t0 / (1.0f + __expf(-t0));
                t1 = t1 / (1.0f + __expf(-t1));
                t2 = t2 / (1.0f + __expf(-t2));
                t3 = t3 / (1.0f + __expf(-t3));
                t4 = t4 / (1.0f + __expf(-t4));
                t5 = t5 / (1.0f + __expf(-t5));
                t6 = t6 / (1.0f + __expf(-t6));
                t7 = t7 / (1.0f + __expf(-t7));
                ssum += t0 * w20.x + t1 * w20.y + t2 * w20.z + t3 * w20.w
                      + t4 * w21.x + t5 * w21.y + t6 * w21.z + t7 * w21.w;
            }
            const float pw = ssum + bp2;
            cdx = fmaf(pw, dx, cdx);
            cdy = fmaf(pw, dy, cdy);
            cdz = fmaf(pw, dz, cdz);
        }
    }
    r1[tid] = cdx; r2[tid] = cdy; r3[tid] = cdz;
    __syncthreads();
    for (int s = 128; s > 0; s >>= 1) {
        if (tid < s) { r1[tid] += r1[tid + s]; r2[tid] += r2[tid + s]; r3[tid] += r3[tid + s]; }
        __syncthreads();
    }
    if (tid == 0) {
        cd_raw[row * 3 + 0] = r1[0];
        cd_raw[row * 3 + 1] = r2[0];
        cd_raw[row * 3 + 2] = r3[0];
    }
}

// ---------------- Kernel 3: proper jax finalize (unchanged, passes) ----------------
__global__ __launch_bounds__(256) void finalize_kernel(
    const float* __restrict__ cd_raw, const int* __restrict__ pad,
    float* __restrict__ out_coord)
{
    const int b = blockIdx.x;
    const int tid = threadIdx.x;
    __shared__ float r1[256], r2[256], r3[256], r4[256];
    float sx = 0.0f, sy = 0.0f, sz = 0.0f, cnt = 0.0f;
    for (int ii = tid; ii < NSEQ; ii += 256) {
        if (pad[b * NSEQ + ii] == 0) {
            sx += cd_raw[(b * NSEQ + ii) * 3 + 0];
            sy += cd_raw[(b * NSEQ + ii) * 3 + 1];
            sz += cd_raw[(b * NSEQ + ii) * 3 + 2];
            cnt += 1.0f;
        }
    }
    r1[tid] = sx; r2[tid] = sy; r3[tid] = sz; r4[tid] = cnt;
    __syncthreads();
    for (int s = 128; s > 0; s >>= 1) {
        if (tid < s) {
            r1[tid] += r1[tid + s]; r2[tid] += r2[tid + s];
            r3[tid] += r3[tid + s]; r4[tid] += r4[tid + s];
        }
        __syncthreads();
    }
    const float denom = fmaxf(r4[0], 1.0f);
    const float inv_d = 1.0f / denom;
    const float mx = r1[0] * inv_d * inv_d;
    const float my = r2[0] * inv_d * inv_d;
    const float mz = r3[0] * inv_d * inv_d;
    for (int ii = tid; ii < NSEQ; ii += 256) {
        const bool v = (pad[b * NSEQ + ii] == 0);
        out_coord[(b * NSEQ + ii) * 3 + 0] = v ? cd_raw[(b * NSEQ + ii) * 3 + 0] * inv_d - mx : 0.0f;
        out_coord[(b * NSEQ + ii) * 3 + 1] = v ? cd_raw[(b * NSEQ + ii) * 3 + 1] * inv_d - my : 0.0f;
        out_coord[(b * NSEQ + ii) * 3 + 2] = v ? cd_raw[(b * NSEQ + ii) * 3 + 2] * inv_d - mz : 0.0f;
    }
}

extern "C" void kernel_launch(void* const* d_in, const int* in_sizes, int n_in,
                              void* d_out, int out_size, void* d_ws, size_t ws_size,
                              hipStream_t stream) {
    const float* trunk  = (const float*)d_in[0];
    const float* coords = (const float*)d_in[1];
    const int*   pad    = (const int*)d_in[2];
    const float* ln_g   = (const float*)d_in[3];
    const float* ln_b   = (const float*)d_in[4];
    const float* w_a1   = (const float*)d_in[5];
    const float* b_a1   = (const float*)d_in[6];
    const float* w_a2   = (const float*)d_in[7];
    const float* b_a2   = (const float*)d_in[8];
    const float* w_pi   = (const float*)d_in[9];
    const float* w_pj   = (const float*)d_in[10];
    const float* w_pr   = (const float*)d_in[11];
    const float* b_p1   = (const float*)d_in[12];
    const float* w_p2   = (const float*)d_in[13];
    const float* b_p2   = (const float*)d_in[14];

    float* out_atom  = (float*)d_out;                 // f32 [0:10240]
    float* out_coord = out_atom + (size_t)BN * AC;    // f32 [10240:16384]

    float* cd_raw = (float*)d_ws;
    float* pj_buf = cd_raw + (size_t)BN * 3;

    row_kernel<<<BN, 256, 0, stream>>>(trunk, pad, ln_g, ln_b, w_a1, b_a1,
                                       w_a2, b_a2, w_pj, out_atom, pj_buf);
    pair_kernel<<<BN, 256, 0, stream>>>(trunk, coords, pad, w_pi, w_pr, b_p1,
                                        w_p2, b_p2, pj_buf, cd_raw);
    finalize_kernel<<<4, 256, 0, stream>>>(cd_raw, pad, out_coord);
}